// Round 8
// baseline (373.502 us; speedup 1.0000x reference)
//
#include <hip/hip_runtime.h>

#define LOG2E 1.4426950408889634f
#define SC2   0.18033688011112042f   // 0.125 * LOG2E

typedef short s16x8 __attribute__((ext_vector_type(8)));
typedef short s16x4 __attribute__((ext_vector_type(4)));
typedef float f32x4 __attribute__((ext_vector_type(4)));
typedef unsigned int u32x4 __attribute__((ext_vector_type(4)));

static __device__ __forceinline__ unsigned short f2bf(float f) {
  return __builtin_bit_cast(unsigned short, (__bf16)f);
}

static __device__ __forceinline__ void gload_lds16(const void* g, void* l) {
  __builtin_amdgcn_global_load_lds(
      (__attribute__((address_space(1))) void*)g,
      (__attribute__((address_space(3))) void*)l, 16, 0, 0);
}

// ---------------- fp32 -> bf16 convert, batched over {q,k,v} ----------------
__global__ void k_f2b(const float* __restrict__ a, const float* __restrict__ b,
                      const float* __restrict__ c, unsigned short* __restrict__ oa,
                      unsigned short* __restrict__ ob, unsigned short* __restrict__ oc) {
  const int z = blockIdx.y;
  const float* in = z == 0 ? a : z == 1 ? b : c;
  unsigned short* out = z == 0 ? oa : z == 1 ? ob : oc;
  int i = blockIdx.x * blockDim.x + threadIdx.x;
  const float4 v = ((const float4*)in)[i];
  ushort4 o;
  o.x = f2bf(v.x); o.y = f2bf(v.y); o.z = f2bf(v.z); o.w = f2bf(v.w);
  ((ushort4*)out)[i] = o;
}

// ---------------- build W_big^T (bf16, [n][k]) — coalesced LDS transpose ----
struct WArgs {
  const float* w[16];      // 4 weight sets x {r,i,j,k}
  unsigned short* dst[4];
};
__global__ void k_build_w(WArgs args) {
  __shared__ float tile[64][65];
  const int z = blockIdx.y;
  const int k0 = (blockIdx.x & 15) * 64, n0 = (blockIdx.x >> 4) * 64;
  const int a = k0 >> 8, c = n0 >> 8;
  const int   selr[16] = {0,1,2,3, 1,0,3,2, 2,3,0,1, 3,2,1,0};
  const float sgnr[16] = {1,1,1,1, -1,1,-1,1, -1,1,1,-1, -1,-1,1,1};
  const float* sp = args.w[z*4 + selr[a*4 + c]];
  const float sg = sgnr[a*4 + c];
  unsigned short* Wt = args.dst[z];
  const int k0l = k0 & 255, n0l = n0 & 255;
  const int rr = threadIdx.x >> 6, cc = threadIdx.x & 63;
#pragma unroll
  for (int p = 0; p < 16; ++p) {
    int r = p*4 + rr;
    tile[r][cc] = sp[(k0l + r)*256 + n0l + cc];   // coalesced read
  }
  __syncthreads();
#pragma unroll
  for (int p = 0; p < 16; ++p) {
    int nn = p*4 + rr;
    Wt[(size_t)(n0 + nn)*1024 + k0 + cc] = f2bf(tile[cc][nn] * sg);  // coalesced write
  }
}

// ---------------- batched QKV GEMM (2-phase double-buffered LDS) ----------------
__global__ __launch_bounds__(256, 2) void k_gemm_qkv(
    const unsigned short* __restrict__ Xq, const unsigned short* __restrict__ Xk,
    const unsigned short* __restrict__ Xv,
    const unsigned short* __restrict__ Wq, const unsigned short* __restrict__ Wk,
    const unsigned short* __restrict__ Wv,
    const float* __restrict__ bq, const float* __restrict__ bk, const float* __restrict__ bv,
    unsigned short* __restrict__ Qp, unsigned short* __restrict__ Kp,
    unsigned short* __restrict__ VpT) {
  __shared__ unsigned short As[2][128*32];
  __shared__ unsigned short Bs[2][128*32];
  const int z = blockIdx.z;
  const unsigned short* A  = z == 0 ? Xq : z == 1 ? Xk : Xv;
  const unsigned short* Bt = z == 0 ? Wq : z == 1 ? Wk : Wv;
  const float* bias        = z == 0 ? bq : z == 1 ? bk : bv;
  const int K = 1024, N = 1024;
  const int tid = threadIdx.x;
  const int lane = tid & 63, wave = tid >> 6;
  const int lo = lane & 15, hi = lane >> 4;
  const int m0 = blockIdx.x * 128, n0 = blockIdx.y * 128;
  const int wr_ = (wave >> 1) * 64, wc_ = (wave & 1) * 64;
  const int e0 = tid*8, e1 = 2048 + tid*8;
  const int r0 = e0 >> 5, c0 = e0 & 31, r1 = e1 >> 5, c1 = e1 & 31;
  f32x4 acc[4][4] = {};

  gload_lds16(A  + (size_t)(m0 + r0)*K + c0, &As[0][e0]);
  gload_lds16(Bt + (size_t)(n0 + r0)*K + c0, &Bs[0][e0]);
  gload_lds16(A  + (size_t)(m0 + r1)*K + c1, &As[0][e1]);
  gload_lds16(Bt + (size_t)(n0 + r1)*K + c1, &Bs[0][e1]);
  __syncthreads();
  int cur = 0;
  for (int k0 = 0; k0 < K; k0 += 32) {
    if (k0 + 32 < K) {
      int kn = k0 + 32;
      gload_lds16(A  + (size_t)(m0 + r0)*K + (kn + c0), &As[cur^1][e0]);
      gload_lds16(Bt + (size_t)(n0 + r0)*K + (kn + c0), &Bs[cur^1][e0]);
      gload_lds16(A  + (size_t)(m0 + r1)*K + (kn + c1), &As[cur^1][e1]);
      gload_lds16(Bt + (size_t)(n0 + r1)*K + (kn + c1), &Bs[cur^1][e1]);
    }
    s16x8 af[4], bfv[4];
#pragma unroll
    for (int mf = 0; mf < 4; ++mf)
      af[mf] = __builtin_bit_cast(s16x8, *(const u32x4*)&As[cur][(wr_ + mf*16 + lo)*32 + hi*8]);
#pragma unroll
    for (int nf = 0; nf < 4; ++nf)
      bfv[nf] = __builtin_bit_cast(s16x8, *(const u32x4*)&Bs[cur][(wc_ + nf*16 + lo)*32 + hi*8]);
#pragma unroll
    for (int mf = 0; mf < 4; ++mf)
#pragma unroll
      for (int nf = 0; nf < 4; ++nf)
        acc[mf][nf] = __builtin_amdgcn_mfma_f32_16x16x32_bf16(af[mf], bfv[nf], acc[mf][nf], 0, 0, 0);
    __syncthreads();
    cur ^= 1;
  }
  if (z < 2) {
    unsigned short* Cout = z == 0 ? Qp : Kp;
#pragma unroll
    for (int nf = 0; nf < 4; ++nf) {
      int col = n0 + wc_ + nf*16 + lo;
      float bv2 = bias[col];
#pragma unroll
      for (int mf = 0; mf < 4; ++mf)
#pragma unroll
        for (int j = 0; j < 4; ++j) {
          int row = m0 + wr_ + mf*16 + hi*4 + j;
          Cout[(size_t)row*N + col] = f2bf(acc[mf][nf][j] + bv2);
        }
    }
  } else {
#pragma unroll
    for (int nf = 0; nf < 4; ++nf) {
      int col = n0 + wc_ + nf*16 + lo;          // h*64 + dk
      float bv2 = bias[col];
      int hh = col >> 6, dk = col & 63;
#pragma unroll
      for (int mf = 0; mf < 4; ++mf) {
        int row = m0 + wr_ + mf*16 + hi*4;      // b*1024 + t (4 consecutive t)
        int bb = row >> 10, t = row & 1023;
        s16x4 pk;
#pragma unroll
        for (int j = 0; j < 4; ++j) pk[j] = (short)f2bf(acc[mf][nf][j] + bv2);
        *(s16x4*)(VpT + ((size_t)((bb*16 + hh)*64 + dk))*1024 + t) = pk;
      }
    }
  }
}

// ---------------- O-projection GEMM (f32 out, 2-phase dbuf) ----------------
__global__ __launch_bounds__(256, 2) void k_gemm_o(
    const unsigned short* __restrict__ A, const unsigned short* __restrict__ Bt,
    const float* __restrict__ bias, float* __restrict__ Cout) {
  __shared__ unsigned short As[2][128*32];
  __shared__ unsigned short Bs[2][128*32];
  const int K = 1024, N = 1024;
  const int tid = threadIdx.x;
  const int lane = tid & 63, wave = tid >> 6;
  const int lo = lane & 15, hi = lane >> 4;
  const int m0 = blockIdx.x * 128, n0 = blockIdx.y * 128;
  const int wr_ = (wave >> 1) * 64, wc_ = (wave & 1) * 64;
  const int e0 = tid*8, e1 = 2048 + tid*8;
  const int r0 = e0 >> 5, c0 = e0 & 31, r1 = e1 >> 5, c1 = e1 & 31;
  f32x4 acc[4][4] = {};
  gload_lds16(A  + (size_t)(m0 + r0)*K + c0, &As[0][e0]);
  gload_lds16(Bt + (size_t)(n0 + r0)*K + c0, &Bs[0][e0]);
  gload_lds16(A  + (size_t)(m0 + r1)*K + c1, &As[0][e1]);
  gload_lds16(Bt + (size_t)(n0 + r1)*K + c1, &Bs[0][e1]);
  __syncthreads();
  int cur = 0;
  for (int k0 = 0; k0 < K; k0 += 32) {
    if (k0 + 32 < K) {
      int kn = k0 + 32;
      gload_lds16(A  + (size_t)(m0 + r0)*K + (kn + c0), &As[cur^1][e0]);
      gload_lds16(Bt + (size_t)(n0 + r0)*K + (kn + c0), &Bs[cur^1][e0]);
      gload_lds16(A  + (size_t)(m0 + r1)*K + (kn + c1), &As[cur^1][e1]);
      gload_lds16(Bt + (size_t)(n0 + r1)*K + (kn + c1), &Bs[cur^1][e1]);
    }
    s16x8 af[4], bfv[4];
#pragma unroll
    for (int mf = 0; mf < 4; ++mf)
      af[mf] = __builtin_bit_cast(s16x8, *(const u32x4*)&As[cur][(wr_ + mf*16 + lo)*32 + hi*8]);
#pragma unroll
    for (int nf = 0; nf < 4; ++nf)
      bfv[nf] = __builtin_bit_cast(s16x8, *(const u32x4*)&Bs[cur][(wc_ + nf*16 + lo)*32 + hi*8]);
#pragma unroll
    for (int mf = 0; mf < 4; ++mf)
#pragma unroll
      for (int nf = 0; nf < 4; ++nf)
        acc[mf][nf] = __builtin_amdgcn_mfma_f32_16x16x32_bf16(af[mf], bfv[nf], acc[mf][nf], 0, 0, 0);
    __syncthreads();
    cur ^= 1;
  }
#pragma unroll
  for (int nf = 0; nf < 4; ++nf) {
    int col = n0 + wc_ + nf*16 + lo;
    float bv2 = bias[col];
#pragma unroll
    for (int mf = 0; mf < 4; ++mf)
#pragma unroll
      for (int j = 0; j < 4; ++j) {
        int row = m0 + wr_ + mf*16 + hi*4 + j;
        Cout[(size_t)row*N + col] = acc[mf][nf][j] + bv2;
      }
  }
}

// ---------------- fused quaternion flash attention (intra-block split-t) ----
// 512 threads = 8 waves: waves 0-3 -> t in [0,512), waves 4-7 -> t in [512,1024),
// same 64 q-rows. No-max softmax => partials combine by addition (LDS at end).
// grid 512: bh = blockIdx&31 (XCD-local), qb = blockIdx>>5.
__global__ __launch_bounds__(512, 4) void k_attn(
    const unsigned short* __restrict__ Qp, const unsigned short* __restrict__ Kp,
    const unsigned short* __restrict__ VpT, const int* __restrict__ mask,
    unsigned short* __restrict__ O) {
  __shared__ float mbias[1024];       // 0 or -2e9 (pre-scaled for exp2 arg)
  __shared__ float cmb[4][4352];      // per-qwave combine region: 4096 acc + 256 lsum
  const int bh = blockIdx.x & 31, qb = blockIdx.x >> 5;
  const int b = bh >> 4, h = bh & 15;
  for (int t = threadIdx.x; t < 1024; t += 512)
    mbias[t] = mask[b*1024 + t] ? 0.0f : -2.0e9f;
  __syncthreads();
  const int lane = threadIdx.x & 63, wave = threadIdx.x >> 6;
  const int qwave = wave & 3, tc = wave >> 2;
  const int lo = lane & 15, hi = lane >> 4;
  const int s0 = qb*64 + qwave*16;

  const int qsel[16] = {0,1,2,3, 1,0,3,2, 2,3,0,1, 3,2,1,0};
  const int qsgn[16] = {1,-1,-1,-1, 1,1,-1,1, 1,1,1,-1, 1,-1,1,1};
  const int vsgn[16] = {1,1,1,1, -1,1,-1,1, -1,1,1,-1, -1,-1,1,1};

  // q~ fragments: B-operand of swapped QK^T (lane: q~[s=lo][d = kb*32 + hi*8 + e])
  s16x8 qf[4][2];
  {
    const size_t qoff = ((size_t)(b*1024 + s0 + lo))*1024 + h*64;
    const int ch_hi = hi >> 1, dlo = (hi & 1) * 8;
#pragma unroll
    for (int c = 0; c < 4; ++c)
#pragma unroll
      for (int kb = 0; kb < 2; ++kb) {
        int ch = kb*2 + ch_hi;
        int p = qsel[c*4 + ch];
        u32x4 raw = *(const u32x4*)(Qp + qoff + p*16 + dlo);
        unsigned int mk = (qsgn[c*4 + ch] < 0) ? 0x80008000u : 0u;
        raw ^= mk;
        qf[c][kb] = __builtin_bit_cast(s16x8, raw);
      }
  }

  f32x4 acc[4][4] = {};          // [comp][d-chunk]; lane holds rows s = hi*4+j
  float lsum[4] = {0.f, 0.f, 0.f, 0.f};

  const unsigned short* vtb = VpT + ((size_t)bh*64 + lo)*1024;
  const int tbeg = tc * 512, tend = tbeg + 512;

  for (int t0 = tbeg; t0 < tend; t0 += 32) {
    const size_t koffA = ((size_t)(b*1024 + t0 + lo))*1024 + h*64;
    s16x8 kfA0 = __builtin_bit_cast(s16x8, *(const u32x4*)(Kp + koffA + hi*8));
    s16x8 kfA1 = __builtin_bit_cast(s16x8, *(const u32x4*)(Kp + koffA + 32 + hi*8));
    const size_t koffB = koffA + (size_t)16*1024;
    s16x8 kfB0 = __builtin_bit_cast(s16x8, *(const u32x4*)(Kp + koffB + hi*8));
    s16x8 kfB1 = __builtin_bit_cast(s16x8, *(const u32x4*)(Kp + koffB + 32 + hi*8));
    s16x4 vA[4], vB[4], vAn[4], vBn[4];
#pragma unroll
    for (int g = 0; g < 4; ++g) {
      vA[g] = *(const s16x4*)(vtb + (size_t)g*16*1024 + t0 + hi*4);
      vB[g] = *(const s16x4*)(vtb + (size_t)g*16*1024 + t0 + 16 + hi*4);
    }
    vAn[0] = vA[0]; vBn[0] = vB[0];
#pragma unroll
    for (int g = 1; g < 4; ++g) {
      vAn[g] = vA[g] ^ (short)0x8000;
      vBn[g] = vB[g] ^ (short)0x8000;
    }
    f32x4 mbA = *(const f32x4*)&mbias[t0 + hi*4];
    f32x4 mbB = *(const f32x4*)&mbias[t0 + 16 + hi*4];

#pragma unroll
    for (int c = 0; c < 4; ++c) {
      f32x4 sA = {0.f,0.f,0.f,0.f}, sB = {0.f,0.f,0.f,0.f};
      sA = __builtin_amdgcn_mfma_f32_16x16x32_bf16(kfA0, qf[c][0], sA, 0, 0, 0);
      sA = __builtin_amdgcn_mfma_f32_16x16x32_bf16(kfA1, qf[c][1], sA, 0, 0, 0);
      sB = __builtin_amdgcn_mfma_f32_16x16x32_bf16(kfB0, qf[c][0], sB, 0, 0, 0);
      sB = __builtin_amdgcn_mfma_f32_16x16x32_bf16(kfB1, qf[c][1], sB, 0, 0, 0);
      float p0 = __builtin_exp2f(__builtin_fmaf(sA[0], SC2, mbA[0]));
      float p1 = __builtin_exp2f(__builtin_fmaf(sA[1], SC2, mbA[1]));
      float p2 = __builtin_exp2f(__builtin_fmaf(sA[2], SC2, mbA[2]));
      float p3 = __builtin_exp2f(__builtin_fmaf(sA[3], SC2, mbA[3]));
      float p4 = __builtin_exp2f(__builtin_fmaf(sB[0], SC2, mbB[0]));
      float p5 = __builtin_exp2f(__builtin_fmaf(sB[1], SC2, mbB[1]));
      float p6 = __builtin_exp2f(__builtin_fmaf(sB[2], SC2, mbB[2]));
      float p7 = __builtin_exp2f(__builtin_fmaf(sB[3], SC2, mbB[3]));
      lsum[c] += ((p0 + p1) + (p2 + p3)) + ((p4 + p5) + (p6 + p7));
      s16x4 pfA, pfB;
      pfA[0] = (short)f2bf(p0); pfA[1] = (short)f2bf(p1);
      pfA[2] = (short)f2bf(p2); pfA[3] = (short)f2bf(p3);
      pfB[0] = (short)f2bf(p4); pfB[1] = (short)f2bf(p5);
      pfB[2] = (short)f2bf(p6); pfB[3] = (short)f2bf(p7);
#pragma unroll
      for (int g = 0; g < 4; ++g) {
        int idx = c*4 + g;
        int p = qsel[idx];
        s16x4 va = vsgn[idx] < 0 ? vAn[p] : vA[p];
        s16x4 vb = vsgn[idx] < 0 ? vBn[p] : vB[p];
        acc[c][g] = __builtin_amdgcn_mfma_f32_16x16x16bf16_1k(pfA, va, acc[c][g], 0, 0, 0);
        acc[c][g] = __builtin_amdgcn_mfma_f32_16x16x16bf16_1k(pfB, vb, acc[c][g], 0, 0, 0);
      }
    }
  }

  // combine the two t-halves via LDS (upper waves publish, lower waves add)
  if (tc == 1) {
    float* R = &cmb[qwave][0];
#pragma unroll
    for (int c = 0; c < 4; ++c)
#pragma unroll
      for (int g = 0; g < 4; ++g)
        *(f32x4*)&R[(c*4 + g)*256 + lane*4] = acc[c][g];
#pragma unroll
    for (int c = 0; c < 4; ++c) R[4096 + c*64 + lane] = lsum[c];
  }
  __syncthreads();
  if (tc == 1) return;
  {
    const float* R = &cmb[qwave][0];
#pragma unroll
    for (int c = 0; c < 4; ++c) {
#pragma unroll
      for (int g = 0; g < 4; ++g)
        acc[c][g] += *(const f32x4*)&R[(c*4 + g)*256 + lane*4];
      lsum[c] += R[4096 + c*64 + lane];
    }
  }
  float rl[4];
#pragma unroll
  for (int c = 0; c < 4; ++c) {
    float l = lsum[c];
    l += __shfl_xor(l, 16);
    l += __shfl_xor(l, 32);
    rl[c] = 1.0f / l;
  }
  const size_t obase = ((size_t)(b*1024 + s0 + hi*4))*1024 + h*64;
#pragma unroll
  for (int j = 0; j < 4; ++j) {
    float r0 = __shfl(rl[0], hi*4 + j);
    float r1 = __shfl(rl[1], hi*4 + j);
    float r2 = __shfl(rl[2], hi*4 + j);
    float r3 = __shfl(rl[3], hi*4 + j);
#pragma unroll
    for (int g = 0; g < 4; ++g) {
      float o = acc[0][g][j]*r0 + acc[1][g][j]*r1 + acc[2][g][j]*r2 + acc[3][g][j]*r3;
      O[obase + (size_t)j*1024 + g*16 + lo] = f2bf(o);
    }
  }
}

extern "C" void kernel_launch(void* const* d_in, const int* in_sizes, int n_in,
                              void* d_out, int out_size, void* d_ws, size_t ws_size,
                              hipStream_t stream) {
  const float* q  = (const float*)d_in[0];
  const float* k  = (const float*)d_in[1];
  const float* v  = (const float*)d_in[2];
  const int* mask = (const int*)d_in[3];
  const float* bq = (const float*)d_in[20];
  const float* bk = (const float*)d_in[21];
  const float* bv = (const float*)d_in[22];
  const float* bo = (const float*)d_in[23];

  unsigned short* ws = (unsigned short*)d_ws;
  unsigned short* Xq = ws;                       // 2048*1024 each
  unsigned short* Xk = Xq + 2048*1024;
  unsigned short* Xv = Xk + 2048*1024;
  unsigned short* Wq = Xv + 2048*1024;           // 1024*1024 each
  unsigned short* Wk = Wq + 1024*1024;
  unsigned short* Wv = Wk + 1024*1024;
  unsigned short* Wo = Wv + 1024*1024;
  unsigned short* Qp = Wo + 1024*1024;           // 2048*1024 each
  unsigned short* Kp = Qp + 2048*1024;
  unsigned short* VpT = Kp + 2048*1024;
  unsigned short* Ob = VpT + 2048*1024;

  k_f2b<<<dim3(2048, 3), 256, 0, stream>>>(q, k, v, Xq, Xk, Xv);

  WArgs wa;
  for (int i = 0; i < 16; ++i) wa.w[i] = (const float*)d_in[4 + i];
  wa.dst[0] = Wq; wa.dst[1] = Wk; wa.dst[2] = Wv; wa.dst[3] = Wo;
  k_build_w<<<dim3(256, 4), 256, 0, stream>>>(wa);

  k_gemm_qkv<<<dim3(16, 8, 3), 256, 0, stream>>>(Xq, Xk, Xv, Wq, Wk, Wv,
                                                 bq, bk, bv, Qp, Kp, VpT);
  k_attn<<<512, 512, 0, stream>>>(Qp, Kp, VpT, mask, Ob);
  k_gemm_o<<<dim3(16, 8), 256, 0, stream>>>(Ob, Wo, bo, (float*)d_out);
}

// Round 10
// 267.869 us; speedup vs baseline: 1.3943x; 1.3943x over previous
//
#include <hip/hip_runtime.h>

#define LOG2E 1.4426950408889634f
#define SC2   0.18033688011112042f   // 0.125 * LOG2E

typedef short s16x8 __attribute__((ext_vector_type(8)));
typedef short s16x4 __attribute__((ext_vector_type(4)));
typedef float f32x4 __attribute__((ext_vector_type(4)));
typedef unsigned int u32x4 __attribute__((ext_vector_type(4)));

static __device__ __forceinline__ unsigned short f2bf(float f) {
  return __builtin_bit_cast(unsigned short, (__bf16)f);
}
static __device__ __forceinline__ float bf2f(unsigned short u) {
  return __builtin_bit_cast(float, ((unsigned int)u) << 16);
}

static __device__ __forceinline__ void gload_lds16(const void* g, void* l) {
  __builtin_amdgcn_global_load_lds(
      (__attribute__((address_space(1))) void*)g,
      (__attribute__((address_space(3))) void*)l, 16, 0, 0);
}

// ---------------- fp32 -> bf16 convert, batched over {q,k,v} ----------------
__global__ void k_f2b(const float* __restrict__ a, const float* __restrict__ b,
                      const float* __restrict__ c, unsigned short* __restrict__ oa,
                      unsigned short* __restrict__ ob, unsigned short* __restrict__ oc) {
  const int z = blockIdx.y;
  const float* in = z == 0 ? a : z == 1 ? b : c;
  unsigned short* out = z == 0 ? oa : z == 1 ? ob : oc;
  int i = blockIdx.x * blockDim.x + threadIdx.x;
  const float4 v = ((const float4*)in)[i];
  ushort4 o;
  o.x = f2bf(v.x); o.y = f2bf(v.y); o.z = f2bf(v.z); o.w = f2bf(v.w);
  ((ushort4*)out)[i] = o;
}

// ---------------- build W_big^T (bf16, [n][k]) — coalesced LDS transpose ----
struct WArgs {
  const float* w[16];      // 4 weight sets x {r,i,j,k}
  unsigned short* dst[4];
};
__global__ void k_build_w(WArgs args) {
  __shared__ float tile[64][65];
  const int z = blockIdx.y;
  const int k0 = (blockIdx.x & 15) * 64, n0 = (blockIdx.x >> 4) * 64;
  const int a = k0 >> 8, c = n0 >> 8;
  const int   selr[16] = {0,1,2,3, 1,0,3,2, 2,3,0,1, 3,2,1,0};
  const float sgnr[16] = {1,1,1,1, -1,1,-1,1, -1,1,1,-1, -1,-1,1,1};
  const float* sp = args.w[z*4 + selr[a*4 + c]];
  const float sg = sgnr[a*4 + c];
  unsigned short* Wt = args.dst[z];
  const int k0l = k0 & 255, n0l = n0 & 255;
  const int rr = threadIdx.x >> 6, cc = threadIdx.x & 63;
#pragma unroll
  for (int p = 0; p < 16; ++p) {
    int r = p*4 + rr;
    tile[r][cc] = sp[(k0l + r)*256 + n0l + cc];   // coalesced read
  }
  __syncthreads();
#pragma unroll
  for (int p = 0; p < 16; ++p) {
    int nn = p*4 + rr;
    Wt[(size_t)(n0 + nn)*1024 + k0 + cc] = f2bf(tile[cc][nn] * sg);  // coalesced write
  }
}

// ---------------- batched QKV GEMM (2-phase double-buffered LDS) ----------------
__global__ __launch_bounds__(256, 2) void k_gemm_qkv(
    const unsigned short* __restrict__ Xq, const unsigned short* __restrict__ Xk,
    const unsigned short* __restrict__ Xv,
    const unsigned short* __restrict__ Wq, const unsigned short* __restrict__ Wk,
    const unsigned short* __restrict__ Wv,
    const float* __restrict__ bq, const float* __restrict__ bk, const float* __restrict__ bv,
    unsigned short* __restrict__ Qp, unsigned short* __restrict__ Kp,
    unsigned short* __restrict__ VpT) {
  __shared__ unsigned short As[2][128*32];
  __shared__ unsigned short Bs[2][128*32];
  const int z = blockIdx.z;
  const unsigned short* A  = z == 0 ? Xq : z == 1 ? Xk : Xv;
  const unsigned short* Bt = z == 0 ? Wq : z == 1 ? Wk : Wv;
  const float* bias        = z == 0 ? bq : z == 1 ? bk : bv;
  const int K = 1024, N = 1024;
  const int tid = threadIdx.x;
  const int lane = tid & 63, wave = tid >> 6;
  const int lo = lane & 15, hi = lane >> 4;
  const int m0 = blockIdx.x * 128, n0 = blockIdx.y * 128;
  const int wr_ = (wave >> 1) * 64, wc_ = (wave & 1) * 64;
  const int e0 = tid*8, e1 = 2048 + tid*8;
  const int r0 = e0 >> 5, c0 = e0 & 31, r1 = e1 >> 5, c1 = e1 & 31;
  f32x4 acc[4][4] = {};

  gload_lds16(A  + (size_t)(m0 + r0)*K + c0, &As[0][e0]);
  gload_lds16(Bt + (size_t)(n0 + r0)*K + c0, &Bs[0][e0]);
  gload_lds16(A  + (size_t)(m0 + r1)*K + c1, &As[0][e1]);
  gload_lds16(Bt + (size_t)(n0 + r1)*K + c1, &Bs[0][e1]);
  __syncthreads();
  int cur = 0;
  for (int k0 = 0; k0 < K; k0 += 32) {
    if (k0 + 32 < K) {
      int kn = k0 + 32;
      gload_lds16(A  + (size_t)(m0 + r0)*K + (kn + c0), &As[cur^1][e0]);
      gload_lds16(Bt + (size_t)(n0 + r0)*K + (kn + c0), &Bs[cur^1][e0]);
      gload_lds16(A  + (size_t)(m0 + r1)*K + (kn + c1), &As[cur^1][e1]);
      gload_lds16(Bt + (size_t)(n0 + r1)*K + (kn + c1), &Bs[cur^1][e1]);
    }
    s16x8 af[4], bfv[4];
#pragma unroll
    for (int mf = 0; mf < 4; ++mf)
      af[mf] = __builtin_bit_cast(s16x8, *(const u32x4*)&As[cur][(wr_ + mf*16 + lo)*32 + hi*8]);
#pragma unroll
    for (int nf = 0; nf < 4; ++nf)
      bfv[nf] = __builtin_bit_cast(s16x8, *(const u32x4*)&Bs[cur][(wc_ + nf*16 + lo)*32 + hi*8]);
#pragma unroll
    for (int mf = 0; mf < 4; ++mf)
#pragma unroll
      for (int nf = 0; nf < 4; ++nf)
        acc[mf][nf] = __builtin_amdgcn_mfma_f32_16x16x32_bf16(af[mf], bfv[nf], acc[mf][nf], 0, 0, 0);
    __syncthreads();
    cur ^= 1;
  }
  if (z < 2) {
    unsigned short* Cout = z == 0 ? Qp : Kp;
#pragma unroll
    for (int nf = 0; nf < 4; ++nf) {
      int col = n0 + wc_ + nf*16 + lo;
      float bv2 = bias[col];
#pragma unroll
      for (int mf = 0; mf < 4; ++mf)
#pragma unroll
        for (int j = 0; j < 4; ++j) {
          int row = m0 + wr_ + mf*16 + hi*4 + j;
          Cout[(size_t)row*N + col] = f2bf(acc[mf][nf][j] + bv2);
        }
    }
  } else {
#pragma unroll
    for (int nf = 0; nf < 4; ++nf) {
      int col = n0 + wc_ + nf*16 + lo;          // h*64 + dk
      float bv2 = bias[col];
      int hh = col >> 6, dk = col & 63;
#pragma unroll
      for (int mf = 0; mf < 4; ++mf) {
        int row = m0 + wr_ + mf*16 + hi*4;      // b*1024 + t (4 consecutive t)
        int bb = row >> 10, t = row & 1023;
        s16x4 pk;
#pragma unroll
        for (int j = 0; j < 4; ++j) pk[j] = (short)f2bf(acc[mf][nf][j] + bv2);
        *(s16x4*)(VpT + ((size_t)((bb*16 + hh)*64 + dk))*1024 + t) = pk;
      }
    }
  }
}

// ---------------- O-projection GEMM (f32 out, 2-phase dbuf) ----------------
__global__ __launch_bounds__(256, 2) void k_gemm_o(
    const unsigned short* __restrict__ A, const unsigned short* __restrict__ Bt,
    const float* __restrict__ bias, float* __restrict__ Cout) {
  __shared__ unsigned short As[2][128*32];
  __shared__ unsigned short Bs[2][128*32];
  const int K = 1024, N = 1024;
  const int tid = threadIdx.x;
  const int lane = tid & 63, wave = tid >> 6;
  const int lo = lane & 15, hi = lane >> 4;
  const int m0 = blockIdx.x * 128, n0 = blockIdx.y * 128;
  const int wr_ = (wave >> 1) * 64, wc_ = (wave & 1) * 64;
  const int e0 = tid*8, e1 = 2048 + tid*8;
  const int r0 = e0 >> 5, c0 = e0 & 31, r1 = e1 >> 5, c1 = e1 & 31;
  f32x4 acc[4][4] = {};
  gload_lds16(A  + (size_t)(m0 + r0)*K + c0, &As[0][e0]);
  gload_lds16(Bt + (size_t)(n0 + r0)*K + c0, &Bs[0][e0]);
  gload_lds16(A  + (size_t)(m0 + r1)*K + c1, &As[0][e1]);
  gload_lds16(Bt + (size_t)(n0 + r1)*K + c1, &Bs[0][e1]);
  __syncthreads();
  int cur = 0;
  for (int k0 = 0; k0 < K; k0 += 32) {
    if (k0 + 32 < K) {
      int kn = k0 + 32;
      gload_lds16(A  + (size_t)(m0 + r0)*K + (kn + c0), &As[cur^1][e0]);
      gload_lds16(Bt + (size_t)(n0 + r0)*K + (kn + c0), &Bs[cur^1][e0]);
      gload_lds16(A  + (size_t)(m0 + r1)*K + (kn + c1), &As[cur^1][e1]);
      gload_lds16(Bt + (size_t)(n0 + r1)*K + (kn + c1), &Bs[cur^1][e1]);
    }
    s16x8 af[4], bfv[4];
#pragma unroll
    for (int mf = 0; mf < 4; ++mf)
      af[mf] = __builtin_bit_cast(s16x8, *(const u32x4*)&As[cur][(wr_ + mf*16 + lo)*32 + hi*8]);
#pragma unroll
    for (int nf = 0; nf < 4; ++nf)
      bfv[nf] = __builtin_bit_cast(s16x8, *(const u32x4*)&Bs[cur][(wc_ + nf*16 + lo)*32 + hi*8]);
#pragma unroll
    for (int mf = 0; mf < 4; ++mf)
#pragma unroll
      for (int nf = 0; nf < 4; ++nf)
        acc[mf][nf] = __builtin_amdgcn_mfma_f32_16x16x32_bf16(af[mf], bfv[nf], acc[mf][nf], 0, 0, 0);
    __syncthreads();
    cur ^= 1;
  }
#pragma unroll
  for (int nf = 0; nf < 4; ++nf) {
    int col = n0 + wc_ + nf*16 + lo;
    float bv2 = bias[col];
#pragma unroll
    for (int mf = 0; mf < 4; ++mf)
#pragma unroll
      for (int j = 0; j < 4; ++j) {
        int row = m0 + wr_ + mf*16 + hi*4 + j;
        Cout[(size_t)row*N + col] = acc[mf][nf][j] + bv2;
      }
  }
}

// ---------------- fused quaternion flash attention (grid split-t) ----------
// grid 1024: bh = blockIdx&31 (XCD-local), qb = (blockIdx>>5)&15, tc = blockIdx>>9.
// Each block: 4 waves x 16 q-rows, t in [tc*512, tc*512+512).
// Writes bf16 acc-partials + reduced lsum partials; k_comb sums & normalizes.
__global__ __launch_bounds__(256, 2) void k_attn(
    const unsigned short* __restrict__ Qp, const unsigned short* __restrict__ Kp,
    const unsigned short* __restrict__ VpT, const int* __restrict__ mask,
    unsigned short* __restrict__ Pacc, float* __restrict__ Plsum) {
  __shared__ float mbias[512];   // 0 or -2e9, this block's t-half
  const int bh = blockIdx.x & 31, qb = (blockIdx.x >> 5) & 15, tc = blockIdx.x >> 9;
  const int b = bh >> 4, h = bh & 15;
  for (int t = threadIdx.x; t < 512; t += 256)
    mbias[t] = mask[b*1024 + tc*512 + t] ? 0.0f : -2.0e9f;
  __syncthreads();
  const int lane = threadIdx.x & 63, wave = threadIdx.x >> 6;
  const int lo = lane & 15, hi = lane >> 4;
  const int s0 = qb*64 + wave*16;

  const int qsel[16] = {0,1,2,3, 1,0,3,2, 2,3,0,1, 3,2,1,0};
  const int qsgn[16] = {1,-1,-1,-1, 1,1,-1,1, 1,1,1,-1, 1,-1,1,1};
  const int vsgn[16] = {1,1,1,1, -1,1,-1,1, -1,1,1,-1, -1,-1,1,1};

  // q~ fragments: B-operand of swapped QK^T (lane: q~[s=lo][d = kb*32 + hi*8 + e])
  s16x8 qf[4][2];
  {
    const size_t qoff = ((size_t)(b*1024 + s0 + lo))*1024 + h*64;
    const int ch_hi = hi >> 1, dlo = (hi & 1) * 8;
#pragma unroll
    for (int c = 0; c < 4; ++c)
#pragma unroll
      for (int kb = 0; kb < 2; ++kb) {
        int ch = kb*2 + ch_hi;
        int p = qsel[c*4 + ch];
        u32x4 raw = *(const u32x4*)(Qp + qoff + p*16 + dlo);
        unsigned int mk = (qsgn[c*4 + ch] < 0) ? 0x80008000u : 0u;
        raw ^= mk;
        qf[c][kb] = __builtin_bit_cast(s16x8, raw);
      }
  }

  f32x4 acc[4][4] = {};          // [comp][d-chunk]; lane holds rows s = hi*4+j
  float lsum[4] = {0.f, 0.f, 0.f, 0.f};

  const unsigned short* vtb = VpT + ((size_t)bh*64 + lo)*1024;
  const int tbeg = tc * 512;

  for (int tl = 0; tl < 512; tl += 32) {
    const int t0 = tbeg + tl;
    const size_t koffA = ((size_t)(b*1024 + t0 + lo))*1024 + h*64;
    s16x8 kfA0 = __builtin_bit_cast(s16x8, *(const u32x4*)(Kp + koffA + hi*8));
    s16x8 kfA1 = __builtin_bit_cast(s16x8, *(const u32x4*)(Kp + koffA + 32 + hi*8));
    const size_t koffB = koffA + (size_t)16*1024;
    s16x8 kfB0 = __builtin_bit_cast(s16x8, *(const u32x4*)(Kp + koffB + hi*8));
    s16x8 kfB1 = __builtin_bit_cast(s16x8, *(const u32x4*)(Kp + koffB + 32 + hi*8));
    s16x4 vA[4], vB[4], vAn[4], vBn[4];
#pragma unroll
    for (int g = 0; g < 4; ++g) {
      vA[g] = *(const s16x4*)(vtb + (size_t)g*16*1024 + t0 + hi*4);
      vB[g] = *(const s16x4*)(vtb + (size_t)g*16*1024 + t0 + 16 + hi*4);
    }
    vAn[0] = vA[0]; vBn[0] = vB[0];
#pragma unroll
    for (int g = 1; g < 4; ++g) {
      vAn[g] = vA[g] ^ (short)0x8000;
      vBn[g] = vB[g] ^ (short)0x8000;
    }
    f32x4 mbA = *(const f32x4*)&mbias[tl + hi*4];
    f32x4 mbB = *(const f32x4*)&mbias[tl + 16 + hi*4];

#pragma unroll
    for (int c = 0; c < 4; ++c) {
      f32x4 sA = {0.f,0.f,0.f,0.f}, sB = {0.f,0.f,0.f,0.f};
      sA = __builtin_amdgcn_mfma_f32_16x16x32_bf16(kfA0, qf[c][0], sA, 0, 0, 0);
      sA = __builtin_amdgcn_mfma_f32_16x16x32_bf16(kfA1, qf[c][1], sA, 0, 0, 0);
      sB = __builtin_amdgcn_mfma_f32_16x16x32_bf16(kfB0, qf[c][0], sB, 0, 0, 0);
      sB = __builtin_amdgcn_mfma_f32_16x16x32_bf16(kfB1, qf[c][1], sB, 0, 0, 0);
      float p0 = __builtin_exp2f(__builtin_fmaf(sA[0], SC2, mbA[0]));
      float p1 = __builtin_exp2f(__builtin_fmaf(sA[1], SC2, mbA[1]));
      float p2 = __builtin_exp2f(__builtin_fmaf(sA[2], SC2, mbA[2]));
      float p3 = __builtin_exp2f(__builtin_fmaf(sA[3], SC2, mbA[3]));
      float p4 = __builtin_exp2f(__builtin_fmaf(sB[0], SC2, mbB[0]));
      float p5 = __builtin_exp2f(__builtin_fmaf(sB[1], SC2, mbB[1]));
      float p6 = __builtin_exp2f(__builtin_fmaf(sB[2], SC2, mbB[2]));
      float p7 = __builtin_exp2f(__builtin_fmaf(sB[3], SC2, mbB[3]));
      lsum[c] += ((p0 + p1) + (p2 + p3)) + ((p4 + p5) + (p6 + p7));
      s16x4 pfA, pfB;
      pfA[0] = (short)f2bf(p0); pfA[1] = (short)f2bf(p1);
      pfA[2] = (short)f2bf(p2); pfA[3] = (short)f2bf(p3);
      pfB[0] = (short)f2bf(p4); pfB[1] = (short)f2bf(p5);
      pfB[2] = (short)f2bf(p6); pfB[3] = (short)f2bf(p7);
#pragma unroll
      for (int g = 0; g < 4; ++g) {
        int idx = c*4 + g;
        int p = qsel[idx];
        s16x4 va = vsgn[idx] < 0 ? vAn[p] : vA[p];
        s16x4 vb = vsgn[idx] < 0 ? vBn[p] : vB[p];
        acc[c][g] = __builtin_amdgcn_mfma_f32_16x16x16bf16_1k(pfA, va, acc[c][g], 0, 0, 0);
        acc[c][g] = __builtin_amdgcn_mfma_f32_16x16x16bf16_1k(pfB, vb, acc[c][g], 0, 0, 0);
      }
    }
  }

  // epilogue: reduce lsum across lanes, store partials (bf16 acc + f32 lsum)
  const int b_idx = (tc*32 + bh)*16 + qb;
#pragma unroll
  for (int c = 0; c < 4; ++c) {
    float l = lsum[c];
    l += __shfl_xor(l, 16);
    l += __shfl_xor(l, 32);
    if (hi == 0) Plsum[b_idx*256 + wave*64 + c*16 + lo] = l;
  }
  unsigned short* pb = Pacc + (size_t)b_idx*16384 + wave*4096;
#pragma unroll
  for (int c = 0; c < 4; ++c)
#pragma unroll
    for (int g = 0; g < 4; ++g) {
      s16x4 pk;
#pragma unroll
      for (int j = 0; j < 4; ++j) pk[j] = (short)f2bf(acc[c][g][j]);
      *(s16x4*)(pb + (c*4 + g)*256 + lane*4) = pk;
    }
}

// ---------------- combine: sum t-halves, normalize, write O ----------------
// grid 512: bh = blockIdx&31, qb = blockIdx>>5; 256 threads (wave = qwave).
__global__ __launch_bounds__(256) void k_comb(
    const unsigned short* __restrict__ Pacc, const float* __restrict__ Plsum,
    unsigned short* __restrict__ O) {
  __shared__ float lsm[2][256];
  const int bh = blockIdx.x & 31, qb = blockIdx.x >> 5;
  const int b = bh >> 4, h = bh & 15;
  const int tid = threadIdx.x;
  const int i0 = (bh*16 + qb)*256, i1 = ((32 + bh)*16 + qb)*256;
  lsm[0][tid] = Plsum[i0 + tid];
  lsm[1][tid] = Plsum[i1 + tid];
  __syncthreads();
  const int lane = tid & 63, wave = tid >> 6;
  const int lo = lane & 15, hi = lane >> 4;
  const size_t a0 = ((size_t)(bh*16 + qb))*16384 + wave*4096;
  const size_t a1 = ((size_t)((32 + bh)*16 + qb))*16384 + wave*4096;
  float rl[4][4];
#pragma unroll
  for (int c = 0; c < 4; ++c)
#pragma unroll
    for (int j = 0; j < 4; ++j) {
      int r = wave*64 + c*16 + hi*4 + j;
      rl[c][j] = 1.0f / (lsm[0][r] + lsm[1][r]);
    }
  f32x4 av[4][4];
#pragma unroll
  for (int c = 0; c < 4; ++c)
#pragma unroll
    for (int g = 0; g < 4; ++g) {
      s16x4 x0 = *(const s16x4*)(Pacc + a0 + (c*4 + g)*256 + lane*4);
      s16x4 x1 = *(const s16x4*)(Pacc + a1 + (c*4 + g)*256 + lane*4);
      f32x4 s;
#pragma unroll
      for (int j = 0; j < 4; ++j)
        s[j] = bf2f((unsigned short)x0[j]) + bf2f((unsigned short)x1[j]);
      av[c][g] = s;
    }
  const int s0 = qb*64 + wave*16;
  const size_t obase = ((size_t)(b*1024 + s0 + hi*4))*1024 + h*64;
#pragma unroll
  for (int j = 0; j < 4; ++j)
#pragma unroll
    for (int g = 0; g < 4; ++g) {
      float o = av[0][g][j]*rl[0][j] + av[1][g][j]*rl[1][j]
              + av[2][g][j]*rl[2][j] + av[3][g][j]*rl[3][j];
      O[obase + (size_t)j*1024 + g*16 + lo] = f2bf(o);
    }
}

extern "C" void kernel_launch(void* const* d_in, const int* in_sizes, int n_in,
                              void* d_out, int out_size, void* d_ws, size_t ws_size,
                              hipStream_t stream) {
  const float* q  = (const float*)d_in[0];
  const float* k  = (const float*)d_in[1];
  const float* v  = (const float*)d_in[2];
  const int* mask = (const int*)d_in[3];
  const float* bq = (const float*)d_in[20];
  const float* bk = (const float*)d_in[21];
  const float* bv = (const float*)d_in[22];
  const float* bo = (const float*)d_in[23];

  const size_t M1 = 1024*1024;
  unsigned short* ws = (unsigned short*)d_ws;
  unsigned short* Xq = ws;                       // 2M shorts each
  unsigned short* Xk = Xq + 2*M1;
  unsigned short* Xv = Xk + 2*M1;
  unsigned short* Wq = Xv + 2*M1;                // 1M shorts each
  unsigned short* Wk = Wq + M1;
  unsigned short* Wv = Wk + M1;
  unsigned short* Wo = Wv + M1;
  unsigned short* Qp = Wo + M1;                  // 2M shorts each
  unsigned short* Kp = Qp + 2*M1;
  unsigned short* VpT = Kp + 2*M1;
  unsigned short* Ob = VpT + 2*M1;
  unsigned short* Pacc = Ob + 2*M1;              // 1024 blocks x 16384 = 16M shorts
  float* Plsum = (float*)(Pacc + 16*M1);         // 1024 x 256 f32

  k_f2b<<<dim3(2048, 3), 256, 0, stream>>>(q, k, v, Xq, Xk, Xv);

  WArgs wa;
  for (int i = 0; i < 16; ++i) wa.w[i] = (const float*)d_in[4 + i];
  wa.dst[0] = Wq; wa.dst[1] = Wk; wa.dst[2] = Wv; wa.dst[3] = Wo;
  k_build_w<<<dim3(256, 4), 256, 0, stream>>>(wa);

  k_gemm_qkv<<<dim3(16, 8, 3), 256, 0, stream>>>(Xq, Xk, Xv, Wq, Wk, Wv,
                                                 bq, bk, bv, Qp, Kp, VpT);
  k_attn<<<1024, 256, 0, stream>>>(Qp, Kp, VpT, mask, Pacc, Plsum);
  k_comb<<<512, 256, 0, stream>>>(Pacc, Plsum, Ob);
  k_gemm_o<<<dim3(16, 8), 256, 0, stream>>>(Ob, Wo, bo, (float*)d_out);
}

// Round 11
// 259.815 us; speedup vs baseline: 1.4376x; 1.0310x over previous
//
#include <hip/hip_runtime.h>

#define LOG2E 1.4426950408889634f
#define SC2   0.18033688011112042f   // 0.125 * LOG2E

typedef short s16x8 __attribute__((ext_vector_type(8)));
typedef short s16x4 __attribute__((ext_vector_type(4)));
typedef float f32x4 __attribute__((ext_vector_type(4)));
typedef unsigned int u32x4 __attribute__((ext_vector_type(4)));

static __device__ __forceinline__ unsigned short f2bf(float f) {
  return __builtin_bit_cast(unsigned short, (__bf16)f);
}

static __device__ __forceinline__ void gload_lds16(const void* g, void* l) {
  __builtin_amdgcn_global_load_lds(
      (__attribute__((address_space(1))) void*)g,
      (__attribute__((address_space(3))) void*)l, 16, 0, 0);
}

// ---------------- fp32 -> bf16 convert, batched over {q,k,v} ----------------
__global__ void k_f2b(const float* __restrict__ a, const float* __restrict__ b,
                      const float* __restrict__ c, unsigned short* __restrict__ oa,
                      unsigned short* __restrict__ ob, unsigned short* __restrict__ oc) {
  const int z = blockIdx.y;
  const float* in = z == 0 ? a : z == 1 ? b : c;
  unsigned short* out = z == 0 ? oa : z == 1 ? ob : oc;
  int i = blockIdx.x * blockDim.x + threadIdx.x;
  const float4 v = ((const float4*)in)[i];
  ushort4 o;
  o.x = f2bf(v.x); o.y = f2bf(v.y); o.z = f2bf(v.z); o.w = f2bf(v.w);
  ((ushort4*)out)[i] = o;
}

// ---------------- build W_big^T (bf16, [n][k]) — coalesced LDS transpose ----
struct WArgs {
  const float* w[16];      // 4 weight sets x {r,i,j,k}
  unsigned short* dst[4];
};
__global__ void k_build_w(WArgs args) {
  __shared__ float tile[64][65];
  const int z = blockIdx.y;
  const int k0 = (blockIdx.x & 15) * 64, n0 = (blockIdx.x >> 4) * 64;
  const int a = k0 >> 8, c = n0 >> 8;
  const int   selr[16] = {0,1,2,3, 1,0,3,2, 2,3,0,1, 3,2,1,0};
  const float sgnr[16] = {1,1,1,1, -1,1,-1,1, -1,1,1,-1, -1,-1,1,1};
  const float* sp = args.w[z*4 + selr[a*4 + c]];
  const float sg = sgnr[a*4 + c];
  unsigned short* Wt = args.dst[z];
  const int k0l = k0 & 255, n0l = n0 & 255;
  const int rr = threadIdx.x >> 6, cc = threadIdx.x & 63;
#pragma unroll
  for (int p = 0; p < 16; ++p) {
    int r = p*4 + rr;
    tile[r][cc] = sp[(k0l + r)*256 + n0l + cc];   // coalesced read
  }
  __syncthreads();
#pragma unroll
  for (int p = 0; p < 16; ++p) {
    int nn = p*4 + rr;
    Wt[(size_t)(n0 + nn)*1024 + k0 + cc] = f2bf(tile[cc][nn] * sg);  // coalesced write
  }
}

// ---------------- batched QKV GEMM (2-phase double-buffered LDS) ----------------
__global__ __launch_bounds__(256, 2) void k_gemm_qkv(
    const unsigned short* __restrict__ Xq, const unsigned short* __restrict__ Xk,
    const unsigned short* __restrict__ Xv,
    const unsigned short* __restrict__ Wq, const unsigned short* __restrict__ Wk,
    const unsigned short* __restrict__ Wv,
    const float* __restrict__ bq, const float* __restrict__ bk, const float* __restrict__ bv,
    unsigned short* __restrict__ Qp, unsigned short* __restrict__ Kp,
    unsigned short* __restrict__ VpT) {
  __shared__ unsigned short As[2][128*32];
  __shared__ unsigned short Bs[2][128*32];
  const int z = blockIdx.z;
  const unsigned short* A  = z == 0 ? Xq : z == 1 ? Xk : Xv;
  const unsigned short* Bt = z == 0 ? Wq : z == 1 ? Wk : Wv;
  const float* bias        = z == 0 ? bq : z == 1 ? bk : bv;
  const int K = 1024, N = 1024;
  const int tid = threadIdx.x;
  const int lane = tid & 63, wave = tid >> 6;
  const int lo = lane & 15, hi = lane >> 4;
  const int m0 = blockIdx.x * 128, n0 = blockIdx.y * 128;
  const int wr_ = (wave >> 1) * 64, wc_ = (wave & 1) * 64;
  const int e0 = tid*8, e1 = 2048 + tid*8;
  const int r0 = e0 >> 5, c0 = e0 & 31, r1 = e1 >> 5, c1 = e1 & 31;
  f32x4 acc[4][4] = {};

  gload_lds16(A  + (size_t)(m0 + r0)*K + c0, &As[0][e0]);
  gload_lds16(Bt + (size_t)(n0 + r0)*K + c0, &Bs[0][e0]);
  gload_lds16(A  + (size_t)(m0 + r1)*K + c1, &As[0][e1]);
  gload_lds16(Bt + (size_t)(n0 + r1)*K + c1, &Bs[0][e1]);
  __syncthreads();
  int cur = 0;
  for (int k0 = 0; k0 < K; k0 += 32) {
    if (k0 + 32 < K) {
      int kn = k0 + 32;
      gload_lds16(A  + (size_t)(m0 + r0)*K + (kn + c0), &As[cur^1][e0]);
      gload_lds16(Bt + (size_t)(n0 + r0)*K + (kn + c0), &Bs[cur^1][e0]);
      gload_lds16(A  + (size_t)(m0 + r1)*K + (kn + c1), &As[cur^1][e1]);
      gload_lds16(Bt + (size_t)(n0 + r1)*K + (kn + c1), &Bs[cur^1][e1]);
    }
    s16x8 af[4], bfv[4];
#pragma unroll
    for (int mf = 0; mf < 4; ++mf)
      af[mf] = __builtin_bit_cast(s16x8, *(const u32x4*)&As[cur][(wr_ + mf*16 + lo)*32 + hi*8]);
#pragma unroll
    for (int nf = 0; nf < 4; ++nf)
      bfv[nf] = __builtin_bit_cast(s16x8, *(const u32x4*)&Bs[cur][(wc_ + nf*16 + lo)*32 + hi*8]);
#pragma unroll
    for (int mf = 0; mf < 4; ++mf)
#pragma unroll
      for (int nf = 0; nf < 4; ++nf)
        acc[mf][nf] = __builtin_amdgcn_mfma_f32_16x16x32_bf16(af[mf], bfv[nf], acc[mf][nf], 0, 0, 0);
    __syncthreads();
    cur ^= 1;
  }
  if (z < 2) {
    unsigned short* Cout = z == 0 ? Qp : Kp;
#pragma unroll
    for (int nf = 0; nf < 4; ++nf) {
      int col = n0 + wc_ + nf*16 + lo;
      float bv2 = bias[col];
#pragma unroll
      for (int mf = 0; mf < 4; ++mf)
#pragma unroll
        for (int j = 0; j < 4; ++j) {
          int row = m0 + wr_ + mf*16 + hi*4 + j;
          Cout[(size_t)row*N + col] = f2bf(acc[mf][nf][j] + bv2);
        }
    }
  } else {
#pragma unroll
    for (int nf = 0; nf < 4; ++nf) {
      int col = n0 + wc_ + nf*16 + lo;          // h*64 + dk
      float bv2 = bias[col];
      int hh = col >> 6, dk = col & 63;
#pragma unroll
      for (int mf = 0; mf < 4; ++mf) {
        int row = m0 + wr_ + mf*16 + hi*4;      // b*1024 + t (4 consecutive t)
        int bb = row >> 10, t = row & 1023;
        s16x4 pk;
#pragma unroll
        for (int j = 0; j < 4; ++j) pk[j] = (short)f2bf(acc[mf][nf][j] + bv2);
        *(s16x4*)(VpT + ((size_t)((bb*16 + hh)*64 + dk))*1024 + t) = pk;
      }
    }
  }
}

// ---------------- O-projection GEMM (f32 out, 2-phase dbuf) ----------------
__global__ __launch_bounds__(256, 2) void k_gemm_o(
    const unsigned short* __restrict__ A, const unsigned short* __restrict__ Bt,
    const float* __restrict__ bias, float* __restrict__ Cout) {
  __shared__ unsigned short As[2][128*32];
  __shared__ unsigned short Bs[2][128*32];
  const int K = 1024, N = 1024;
  const int tid = threadIdx.x;
  const int lane = tid & 63, wave = tid >> 6;
  const int lo = lane & 15, hi = lane >> 4;
  const int m0 = blockIdx.x * 128, n0 = blockIdx.y * 128;
  const int wr_ = (wave >> 1) * 64, wc_ = (wave & 1) * 64;
  const int e0 = tid*8, e1 = 2048 + tid*8;
  const int r0 = e0 >> 5, c0 = e0 & 31, r1 = e1 >> 5, c1 = e1 & 31;
  f32x4 acc[4][4] = {};
  gload_lds16(A  + (size_t)(m0 + r0)*K + c0, &As[0][e0]);
  gload_lds16(Bt + (size_t)(n0 + r0)*K + c0, &Bs[0][e0]);
  gload_lds16(A  + (size_t)(m0 + r1)*K + c1, &As[0][e1]);
  gload_lds16(Bt + (size_t)(n0 + r1)*K + c1, &Bs[0][e1]);
  __syncthreads();
  int cur = 0;
  for (int k0 = 0; k0 < K; k0 += 32) {
    if (k0 + 32 < K) {
      int kn = k0 + 32;
      gload_lds16(A  + (size_t)(m0 + r0)*K + (kn + c0), &As[cur^1][e0]);
      gload_lds16(Bt + (size_t)(n0 + r0)*K + (kn + c0), &Bs[cur^1][e0]);
      gload_lds16(A  + (size_t)(m0 + r1)*K + (kn + c1), &As[cur^1][e1]);
      gload_lds16(Bt + (size_t)(n0 + r1)*K + (kn + c1), &Bs[cur^1][e1]);
    }
    s16x8 af[4], bfv[4];
#pragma unroll
    for (int mf = 0; mf < 4; ++mf)
      af[mf] = __builtin_bit_cast(s16x8, *(const u32x4*)&As[cur][(wr_ + mf*16 + lo)*32 + hi*8]);
#pragma unroll
    for (int nf = 0; nf < 4; ++nf)
      bfv[nf] = __builtin_bit_cast(s16x8, *(const u32x4*)&Bs[cur][(wc_ + nf*16 + lo)*32 + hi*8]);
#pragma unroll
    for (int mf = 0; mf < 4; ++mf)
#pragma unroll
      for (int nf = 0; nf < 4; ++nf)
        acc[mf][nf] = __builtin_amdgcn_mfma_f32_16x16x32_bf16(af[mf], bfv[nf], acc[mf][nf], 0, 0, 0);
    __syncthreads();
    cur ^= 1;
  }
#pragma unroll
  for (int nf = 0; nf < 4; ++nf) {
    int col = n0 + wc_ + nf*16 + lo;
    float bv2 = bias[col];
#pragma unroll
    for (int mf = 0; mf < 4; ++mf)
#pragma unroll
      for (int j = 0; j < 4; ++j) {
        int row = m0 + wr_ + mf*16 + hi*4 + j;
        Cout[(size_t)row*N + col] = acc[mf][nf][j] + bv2;
      }
  }
}

// ---------------- fused quaternion flash attention (depth-1 K/V prefetch) ----
// grid 512: bh = blockIdx&31 (XCD-local), qb = blockIdx>>5; 4 waves x 16 q-rows.
// No-max softmax; per-lane deferred l-sum; 2x-unrolled pipelined main loop.
#define LDK(T0, KA0, KA1, KB0, KB1)                                            \
  do {                                                                         \
    const unsigned short* _ka = Kp + ((size_t)(b*1024 + (T0) + lo))*1024 + h*64; \
    KA0 = __builtin_bit_cast(s16x8, *(const u32x4*)(_ka + hi*8));              \
    KA1 = __builtin_bit_cast(s16x8, *(const u32x4*)(_ka + 32 + hi*8));         \
    KB0 = __builtin_bit_cast(s16x8, *(const u32x4*)(_ka + 16*1024 + hi*8));    \
    KB1 = __builtin_bit_cast(s16x8, *(const u32x4*)(_ka + 16*1024 + 32 + hi*8)); \
  } while (0)

#define LDV(T0, VA, VB)                                                        \
  do {                                                                         \
    _Pragma("unroll")                                                          \
    for (int g = 0; g < 4; ++g) {                                              \
      VA[g] = *(const s16x4*)(vtb + (size_t)g*16*1024 + (T0) + hi*4);          \
      VB[g] = *(const s16x4*)(vtb + (size_t)g*16*1024 + (T0) + 16 + hi*4);     \
    }                                                                          \
  } while (0)

#define CMP(T0, KA0, KA1, KB0, KB1, VA, VB)                                    \
  do {                                                                         \
    s16x4 vAn[4], vBn[4];                                                      \
    vAn[0] = VA[0]; vBn[0] = VB[0];                                            \
    _Pragma("unroll")                                                          \
    for (int g = 1; g < 4; ++g) {                                              \
      vAn[g] = VA[g] ^ (short)0x8000;                                          \
      vBn[g] = VB[g] ^ (short)0x8000;                                          \
    }                                                                          \
    f32x4 mbA = *(const f32x4*)&mbias[(T0) + hi*4];                            \
    f32x4 mbB = *(const f32x4*)&mbias[(T0) + 16 + hi*4];                       \
    _Pragma("unroll")                                                          \
    for (int c = 0; c < 4; ++c) {                                              \
      f32x4 sA = {0.f,0.f,0.f,0.f}, sB = {0.f,0.f,0.f,0.f};                    \
      sA = __builtin_amdgcn_mfma_f32_16x16x32_bf16(KA0, qf[c][0], sA, 0, 0, 0); \
      sA = __builtin_amdgcn_mfma_f32_16x16x32_bf16(KA1, qf[c][1], sA, 0, 0, 0); \
      sB = __builtin_amdgcn_mfma_f32_16x16x32_bf16(KB0, qf[c][0], sB, 0, 0, 0); \
      sB = __builtin_amdgcn_mfma_f32_16x16x32_bf16(KB1, qf[c][1], sB, 0, 0, 0); \
      float p0 = __builtin_exp2f(__builtin_fmaf(sA[0], SC2, mbA[0]));          \
      float p1 = __builtin_exp2f(__builtin_fmaf(sA[1], SC2, mbA[1]));          \
      float p2 = __builtin_exp2f(__builtin_fmaf(sA[2], SC2, mbA[2]));          \
      float p3 = __builtin_exp2f(__builtin_fmaf(sA[3], SC2, mbA[3]));          \
      float p4 = __builtin_exp2f(__builtin_fmaf(sB[0], SC2, mbB[0]));          \
      float p5 = __builtin_exp2f(__builtin_fmaf(sB[1], SC2, mbB[1]));          \
      float p6 = __builtin_exp2f(__builtin_fmaf(sB[2], SC2, mbB[2]));          \
      float p7 = __builtin_exp2f(__builtin_fmaf(sB[3], SC2, mbB[3]));          \
      lsum[c] += ((p0 + p1) + (p2 + p3)) + ((p4 + p5) + (p6 + p7));            \
      s16x4 pfA, pfB;                                                          \
      pfA[0] = (short)f2bf(p0); pfA[1] = (short)f2bf(p1);                      \
      pfA[2] = (short)f2bf(p2); pfA[3] = (short)f2bf(p3);                      \
      pfB[0] = (short)f2bf(p4); pfB[1] = (short)f2bf(p5);                      \
      pfB[2] = (short)f2bf(p6); pfB[3] = (short)f2bf(p7);                      \
      _Pragma("unroll")                                                        \
      for (int g = 0; g < 4; ++g) {                                            \
        int idx = c*4 + g;                                                     \
        int p = qsel[idx];                                                     \
        s16x4 va = vsgn[idx] < 0 ? vAn[p] : VA[p];                             \
        s16x4 vb = vsgn[idx] < 0 ? vBn[p] : VB[p];                             \
        acc[c][g] = __builtin_amdgcn_mfma_f32_16x16x16bf16_1k(pfA, va, acc[c][g], 0, 0, 0); \
        acc[c][g] = __builtin_amdgcn_mfma_f32_16x16x16bf16_1k(pfB, vb, acc[c][g], 0, 0, 0); \
      }                                                                        \
    }                                                                          \
  } while (0)

__global__ __launch_bounds__(256, 2) void k_attn(
    const unsigned short* __restrict__ Qp, const unsigned short* __restrict__ Kp,
    const unsigned short* __restrict__ VpT, const int* __restrict__ mask,
    unsigned short* __restrict__ O) {
  __shared__ float mbias[1024];   // 0 or -2e9 (pre-scaled for exp2 arg)
  const int bh = blockIdx.x & 31, qb = blockIdx.x >> 5;
  const int b = bh >> 4, h = bh & 15;
  for (int t = threadIdx.x; t < 1024; t += 256)
    mbias[t] = mask[b*1024 + t] ? 0.0f : -2.0e9f;
  __syncthreads();
  const int lane = threadIdx.x & 63, wave = threadIdx.x >> 6;
  const int lo = lane & 15, hi = lane >> 4;
  const int s0 = qb*64 + wave*16;

  const int qsel[16] = {0,1,2,3, 1,0,3,2, 2,3,0,1, 3,2,1,0};
  const int qsgn[16] = {1,-1,-1,-1, 1,1,-1,1, 1,1,1,-1, 1,-1,1,1};
  const int vsgn[16] = {1,1,1,1, -1,1,-1,1, -1,1,1,-1, -1,-1,1,1};

  // q~ fragments: B-operand of swapped QK^T (lane: q~[s=lo][d = kb*32 + hi*8 + e])
  s16x8 qf[4][2];
  {
    const size_t qoff = ((size_t)(b*1024 + s0 + lo))*1024 + h*64;
    const int ch_hi = hi >> 1, dlo = (hi & 1) * 8;
#pragma unroll
    for (int c = 0; c < 4; ++c)
#pragma unroll
      for (int kb = 0; kb < 2; ++kb) {
        int ch = kb*2 + ch_hi;
        int p = qsel[c*4 + ch];
        u32x4 raw = *(const u32x4*)(Qp + qoff + p*16 + dlo);
        unsigned int mk = (qsgn[c*4 + ch] < 0) ? 0x80008000u : 0u;
        raw ^= mk;
        qf[c][kb] = __builtin_bit_cast(s16x8, raw);
      }
  }

  f32x4 acc[4][4] = {};          // [comp][d-chunk]; lane holds rows s = hi*4+j
  float lsum[4] = {0.f, 0.f, 0.f, 0.f};

  const unsigned short* vtb = VpT + ((size_t)bh*64 + lo)*1024;

  // pipelined main loop: two named register sets, depth-1 prefetch
  s16x8 kA0_0, kA1_0, kB0_0, kB1_0, kA0_1, kA1_1, kB0_1, kB1_1;
  s16x4 vA_0[4], vB_0[4], vA_1[4], vB_1[4];
  LDK(0, kA0_0, kA1_0, kB0_0, kB1_0);
  LDV(0, vA_0, vB_0);
  for (int t0 = 0; t0 < 1024; t0 += 64) {
    const int t1 = t0 + 32;
    const int t2 = (t0 + 64) & 1023;   // wrap: final prefetch is unused but in-bounds
    LDK(t1, kA0_1, kA1_1, kB0_1, kB1_1);
    LDV(t1, vA_1, vB_1);
    CMP(t0, kA0_0, kA1_0, kB0_0, kB1_0, vA_0, vB_0);
    LDK(t2, kA0_0, kA1_0, kB0_0, kB1_0);
    LDV(t2, vA_0, vB_0);
    CMP(t1, kA0_1, kA1_1, kB0_1, kB1_1, vA_1, vB_1);
  }

  // single cross-lane l reduction (deferred out of the main loop)
  float rl[4];
#pragma unroll
  for (int c = 0; c < 4; ++c) {
    float l = lsum[c];
    l += __shfl_xor(l, 16);
    l += __shfl_xor(l, 32);
    rl[c] = 1.0f / l;
  }
  const size_t obase = ((size_t)(b*1024 + s0 + hi*4))*1024 + h*64;
#pragma unroll
  for (int j = 0; j < 4; ++j) {
    float r0 = __shfl(rl[0], hi*4 + j);
    float r1 = __shfl(rl[1], hi*4 + j);
    float r2 = __shfl(rl[2], hi*4 + j);
    float r3 = __shfl(rl[3], hi*4 + j);
#pragma unroll
    for (int g = 0; g < 4; ++g) {
      float o = acc[0][g][j]*r0 + acc[1][g][j]*r1 + acc[2][g][j]*r2 + acc[3][g][j]*r3;
      O[obase + (size_t)j*1024 + g*16 + lo] = f2bf(o);
    }
  }
}

extern "C" void kernel_launch(void* const* d_in, const int* in_sizes, int n_in,
                              void* d_out, int out_size, void* d_ws, size_t ws_size,
                              hipStream_t stream) {
  const float* q  = (const float*)d_in[0];
  const float* k  = (const float*)d_in[1];
  const float* v  = (const float*)d_in[2];
  const int* mask = (const int*)d_in[3];
  const float* bq = (const float*)d_in[20];
  const float* bk = (const float*)d_in[21];
  const float* bv = (const float*)d_in[22];
  const float* bo = (const float*)d_in[23];

  const size_t M1 = 1024*1024;
  unsigned short* ws = (unsigned short*)d_ws;
  unsigned short* Xq = ws;                       // 2M shorts each
  unsigned short* Xk = Xq + 2*M1;
  unsigned short* Xv = Xk + 2*M1;
  unsigned short* Wq = Xv + 2*M1;                // 1M shorts each
  unsigned short* Wk = Wq + M1;
  unsigned short* Wv = Wk + M1;
  unsigned short* Wo = Wv + M1;
  unsigned short* Qp = Wo + M1;                  // 2M shorts each
  unsigned short* Kp = Qp + 2*M1;
  unsigned short* VpT = Kp + 2*M1;
  unsigned short* Ob = VpT + 2*M1;

  k_f2b<<<dim3(2048, 3), 256, 0, stream>>>(q, k, v, Xq, Xk, Xv);

  WArgs wa;
  for (int i = 0; i < 16; ++i) wa.w[i] = (const float*)d_in[4 + i];
  wa.dst[0] = Wq; wa.dst[1] = Wk; wa.dst[2] = Wv; wa.dst[3] = Wo;
  k_build_w<<<dim3(256, 4), 256, 0, stream>>>(wa);

  k_gemm_qkv<<<dim3(16, 8, 3), 256, 0, stream>>>(Xq, Xk, Xv, Wq, Wk, Wv,
                                                 bq, bk, bv, Qp, Kp, VpT);
  k_attn<<<512, 256, 0, stream>>>(Qp, Kp, VpT, mask, Ob);
  k_gemm_o<<<dim3(16, 8), 256, 0, stream>>>(Ob, Wo, bo, (float*)d_out);
}